// Round 8
// baseline (1003.970 us; speedup 1.0000x reference)
//
#include <hip/hip_runtime.h>
#include <cstdint>

// ---------- types / helpers ----------
typedef __attribute__((ext_vector_type(8))) short short8;   // 8 x bf16
typedef __attribute__((ext_vector_type(4))) float f32x4;
typedef __attribute__((ext_vector_type(2))) float f32x2;
typedef __attribute__((ext_vector_type(4))) int i32x4;
typedef unsigned short us16;
typedef unsigned char u8;

#define DEV __device__ __forceinline__

DEV us16 f2bf(float f){
  union { float f; unsigned u; } v; v.f = f;
  unsigned r = (v.u + 0x7FFFu + ((v.u >> 16) & 1u)) >> 16;   // RNE
  return (us16)r;
}
DEV u8 f2fp8(float f){      // OCP e4m3fn via HW cvt (RNE, saturating)
  int p = __builtin_amdgcn_cvt_pk_fp8_f32(f, f, 0, false);
  return (u8)(p & 0xFF);
}
template<int SEL> DEV float fp8tof(int dw){
#if __has_builtin(__builtin_amdgcn_cvt_f32_fp8)
  return __builtin_amdgcn_cvt_f32_fp8(dw, SEL);
#else
  int b = (dw >> (8*SEL)) & 255;
  int e = (b>>3)&15, m = b&7;
  float v;
  if (e){ union{unsigned u; float f;} x; x.u = (unsigned)(((e+120)<<23) | (m<<20)); v = x.f; }
  else v = (float)m * 0.001953125f;
  return (b & 128) ? -v : v;
#endif
}
DEV f32x4 dq8x4(int dw){
#if __has_builtin(__builtin_amdgcn_cvt_pk_f32_fp8)
  f32x2 lo = __builtin_amdgcn_cvt_pk_f32_fp8(dw, false);
  f32x2 hi = __builtin_amdgcn_cvt_pk_f32_fp8(dw, true);
  return (f32x4){lo.x, lo.y, hi.x, hi.y};
#else
  return (f32x4){fp8tof<0>(dw), fp8tof<1>(dw), fp8tof<2>(dw), fp8tof<3>(dw)};
#endif
}
DEV float fclamp20(float x){ return fminf(fmaxf(x, -20.0f), 20.0f); }
DEV float fsoftplus(float x){
  float ax = fabsf(x);
  float e = __builtin_amdgcn_exp2f(-1.4426950408889634f * ax);
  float l = 0.69314718055994531f * __builtin_amdgcn_logf(1.0f + e);
  return fmaxf(x, 0.0f) + l;
}
DEV f32x4 mfma16f8(long a, long b, f32x4 c){
  return __builtin_amdgcn_mfma_f32_16x16x32_fp8_fp8(a, b, c, 0, 0, 0);
}

// Dims: B=256, T=WN=200, HH=256/dir, gates=1024, tags K=12.
// MFMA 16x16x32 fragments: A: lane L holds A[m=L&15][k=(L>>4)*8+j];
// B: lane L holds B[k=(L>>4)*8+j][n=L&15]; D: lane L reg r = D[(L>>4)*4+r][L&15].
// pi h-permutation: orig col w*32+nt*16+l -> stored w*32+l*2+nt;
// inverse: s -> (s>>5)*32 + (s&1)*16 + ((s&31)>>1)

// ---------- preprocessing ----------

__global__ void k_embed(const int* __restrict__ chars, const float* __restrict__ emb,
                        u8* __restrict__ out){
  int tid = blockIdx.x * 256 + threadIdx.x;          // 256*200*32
  if (tid >= 256*200*32) return;
  int c = tid & 31, bt = tid >> 5;
  int idx = chars[bt];
  float v = (c < 30) ? emb[idx * 30 + c] : 0.0f;
  out[tid] = f2fp8(v);
}

__global__ void k_cvt8(const float* __restrict__ src, u8* __restrict__ dst, int n){
  int tid = blockIdx.x * 256 + threadIdx.x;
  if (tid < n) dst[tid] = f2fp8(src[tid]);
}

// LSTM weights [Whh|Wih] -> fp8, pi-permuted h k-order.
__global__ void k_swz_lstm(const float* __restrict__ Whh, const float* __restrict__ Wih,
                           int I, int KC, u8* __restrict__ dst){
  int tid = blockIdx.x * 256 + threadIdx.x;
  int total = 64 * KC * 512;
  if (tid >= total) return;
  int e = tid & 511, chunk = tid >> 9;
  int L = e >> 3, j = e & 7;
  int kc = chunk % KC; int rem = chunk / KC;
  int nt = rem & 1, gt = (rem >> 1) & 3, w = rem >> 3;
  int g = gt * 256 + w * 32 + nt * 16 + (L & 15);
  int s = kc * 32 + (L >> 4) * 8 + j;
  float v = 0.0f;
  if (s < 256){
    int k = (s >> 5) * 32 + (s & 1) * 16 + ((s & 31) >> 1);
    v = Whh[g * 256 + k];
  } else {
    int xi = s - 256;
    if (xi < I) v = Wih[g * I + xi];
  }
  dst[tid] = f2fp8(v);
}

// Wih (word) B-fragment swizzle: [ntile(64)][kc(4)][lane x 8B]
__global__ void k_swz_gin(const float* __restrict__ Wih, u8* __restrict__ dst){
  int tid = blockIdx.x * 256 + threadIdx.x;          // 64*4*512
  if (tid >= 64*4*512) return;
  int e = tid & 511, chunk = tid >> 9;
  int L = e >> 3, j = e & 7;
  int kc = chunk & 3, ntile = chunk >> 2;
  int g = ntile * 16 + (L & 15);
  int k = kc * 32 + (L >> 4) * 8 + j;
  dst[tid] = f2fp8(Wih[g * 128 + k]);
}

// FF fp8 weight swizzle: [nt][kc(KCs)][lane x 8]; perm => pi within 256-halves
__global__ void k_swz_ff8(const float* __restrict__ W, int N, int Kd, int KCs, int perm,
                          u8* __restrict__ dst, int total){
  int tid = blockIdx.x * 256 + threadIdx.x;
  if (tid >= total) return;
  int e = tid & 511, chunk = tid >> 9;
  int L = e >> 3, j = e & 7;
  int kc = chunk % KCs; int nt = chunk / KCs;
  int g = nt * 16 + (L & 15);
  int s = kc * 32 + (L >> 4) * 8 + j;
  int k;
  if (perm){ int base = s & ~255; int q = s & 255;
             k = base + (q >> 5) * 32 + (q & 1) * 16 + ((q & 31) >> 1); }
  else k = s;
  float v = (g < N && k < Kd) ? W[g * Kd + k] : 0.0f;
  dst[tid] = f2fp8(v);
}

// zero fp8 x_cat pad cols 712..767
__global__ void k_zpad8(u8* __restrict__ xcat){
  int tid = blockIdx.x * 256 + threadIdx.x;          // 51200*56
  if (tid >= 51200 * 56) return;
  int r = tid / 56, c = tid - r * 56;
  xcat[(long)r * 768 + 712 + c] = 0;
}

// ---------- gin precompute: gin = fp8(x @ Wih^T + b), 4 timesteps/block ----------
__global__ __launch_bounds__(512) void k_gin(
    const u8* __restrict__ words_f8, const u8* __restrict__ wswg_f,
    const u8* __restrict__ wswg_b, const float* __restrict__ bias_f,
    const float* __restrict__ bias_b, u8* __restrict__ gin)
{
  const int blk = blockIdx.x;
  const int d = blk / 800, rem = blk - d * 800;
  const int slice = rem / 50, tq = rem - slice * 50;
  const u8* Wsw = d ? wswg_b : wswg_f;
  const float* bias = d ? bias_b : bias_f;
  __shared__ u8 xs[16 * 136];
  __shared__ u8 sbuf[512 * 32];
  const int tid = threadIdx.x;
  const int wv = tid >> 6, L = tid & 63;
  const int lrow = L & 15, lq = L >> 4;
  const long* WswV = (const long*)Wsw;

  long wr[8][4];
  #pragma unroll
  for (int nt = 0; nt < 8; ++nt)
    #pragma unroll
    for (int kc = 0; kc < 4; ++kc)
      wr[nt][kc] = WswV[((wv * 8 + nt) * 4 + kc) * 64 + L];
  float bv[8];
  #pragma unroll
  for (int nt = 0; nt < 8; ++nt) bv[nt] = bias[wv * 128 + nt * 16 + lrow];

  for (int i = 0; i < 4; ++i){
    const int t = tq * 4 + i;
    if (tid < 256){
      int r = tid >> 4, c8 = (tid & 15) * 8;
      *(long*)&xs[r * 136 + c8] =
        *(const long*)&words_f8[((long)(slice * 16 + r) * 200 + t) * 128 + c8];
    }
    __syncthreads();
    f32x4 acc[8];
    #pragma unroll
    for (int nt = 0; nt < 8; ++nt) acc[nt] = (f32x4){bv[nt], bv[nt], bv[nt], bv[nt]};
    #pragma unroll
    for (int kc = 0; kc < 4; ++kc){
      long af = *(const long*)&xs[lrow * 136 + kc * 32 + lq * 8];
      #pragma unroll
      for (int nt = 0; nt < 8; ++nt)
        acc[nt] = mfma16f8(af, wr[nt][kc], acc[nt]);
    }
    #pragma unroll
    for (int nt = 0; nt < 8; ++nt){
      int gcol = wv * 128 + nt * 16 + lrow;
      int gt = gcol >> 8, w2 = (gcol >> 5) & 7, nt2 = (gcol >> 4) & 1;
      int tid2 = w2 * 64 + lq * 16 + lrow;
      #pragma unroll
      for (int r = 0; r < 4; ++r)
        sbuf[tid2 * 32 + gt * 8 + nt2 * 4 + r] = f2fp8(acc[nt][r]);
    }
    __syncthreads();
    long ob = (((long)(d * 16 + slice) * 200 + t) * 512 + tid) * 32;
    *(i32x4*)&gin[ob]      = *(const i32x4*)&sbuf[tid * 32];
    *(i32x4*)&gin[ob + 16] = *(const i32x4*)&sbuf[tid * 32 + 16];
    __syncthreads();
  }
}

// ---------- bidirectional LSTM ----------
// 64 blocks x 512 thr. Weights register-resident; shared-rcp cell math (7 q-ops);
// packed fp8 h; incremental hout pointers; deferred global stores.
template<int KC, int XDIM, int SA, bool GIN>
DEV void lstm_body(u8* abuf, const u8* __restrict__ xbuf, const u8* __restrict__ gin,
                   const u8* __restrict__ Wsw, const float* __restrict__ bias,
                   const int* __restrict__ lens, u8* __restrict__ hout,
                   int b0, int hcol0, bool rev, long ginBase)
{
  constexpr int BUF = 16 * SA;
  const int tid = threadIdx.x;
  const int w = tid >> 6, L = tid & 63;
  const int lrow = L & 15, lq = L >> 4;
  const long* WswV = (const long*)Wsw;

  long wr[4][2][KC];
  #pragma unroll
  for (int gt = 0; gt < 4; ++gt)
    #pragma unroll
    for (int nt = 0; nt < 2; ++nt)
      #pragma unroll
      for (int kc = 0; kc < KC; ++kc)
        wr[gt][nt][kc] = WswV[(((w * 4 + gt) * 2 + nt) * KC + kc) * 64 + L];

  float bv[4][2];
  if constexpr (!GIN){
    #pragma unroll
    for (int gt = 0; gt < 4; ++gt)
      #pragma unroll
      for (int nt = 0; nt < 2; ++nt)
        bv[gt][nt] = bias[gt * 256 + w * 32 + nt * 16 + lrow];
  }

  unsigned lpack = 0;
  #pragma unroll
  for (int r = 0; r < 4; ++r)
    lpack |= (unsigned)lens[b0 + lq * 4 + r] << (8 * r);

  float cst[2][4];
  us16 hst[4];
  #pragma unroll
  for (int r = 0; r < 4; ++r){ hst[r] = 0; cst[0][r] = 0.0f; cst[1][r] = 0.0f; }

  for (int e = tid; e < 16 * 32; e += 512)
    *(long*)&abuf[(e >> 5) * SA + (e & 31) * 8] = 0;

  const int t0 = rev ? 199 : 0;
  const long dstep = rev ? -512 : 512;
  u8* hp[4];
  #pragma unroll
  for (int r = 0; r < 4; ++r)
    hp[r] = hout + ((long)(b0 + lq * 4 + r) * 200 + t0) * 512 + hcol0 + w * 32 + lrow * 2;

  if constexpr (!GIN){
    if (tid < (16 * XDIM) >> 3){
      int r = tid / (XDIM >> 3), c8 = (tid % (XDIM >> 3)) * 8;
      *(long*)&abuf[r * SA + 256 + c8] =
        *(const long*)&xbuf[((long)(b0 + r) * 200 + t0) * XDIM + c8];
    }
  }
  i32x4 gA{}, gB{};
  if constexpr (GIN){
    const u8* gp = gin + ((ginBase + t0) * 512 + tid) * 32;
    gA = *(const i32x4*)gp; gB = *(const i32x4*)(gp + 16);
  }
  __syncthreads();

  for (int tau = 0; tau < 200; ++tau){
    const int t = rev ? (199 - tau) : tau;
    u8* cur = abuf + (tau & 1) * BUF;
    u8* nxt = abuf + ((tau & 1) ^ 1) * BUF;

    f32x4 acc[4][2];
    if constexpr (GIN){
      int g4[8];
      *(i32x4*)&g4[0] = gA; *(i32x4*)&g4[4] = gB;
      #pragma unroll
      for (int gt = 0; gt < 4; ++gt)
        #pragma unroll
        for (int nt = 0; nt < 2; ++nt)
          acc[gt][nt] = dq8x4(g4[gt * 2 + nt]);
      int tn = (tau < 199) ? (rev ? 198 - tau : tau + 1) : t;
      const u8* gp = gin + ((ginBase + tn) * 512 + tid) * 32;
      gA = *(const i32x4*)gp; gB = *(const i32x4*)(gp + 16);
    } else {
      #pragma unroll
      for (int gt = 0; gt < 4; ++gt)
        #pragma unroll
        for (int nt = 0; nt < 2; ++nt)
          acc[gt][nt] = (f32x4){bv[gt][nt], bv[gt][nt], bv[gt][nt], bv[gt][nt]};
    }

    #pragma unroll
    for (int kc = 0; kc < KC; ++kc){
      long af = *(const long*)&cur[lrow * SA + kc * 32 + lq * 8];
      #pragma unroll
      for (int gt = 0; gt < 4; ++gt)
        #pragma unroll
        for (int nt = 0; nt < 2; ++nt)
          acc[gt][nt] = mfma16f8(af, wr[gt][nt][kc], acc[gt][nt]);
    }

    // epilogue: shared-rcp cell math, packed fp8 pair per r
    us16 houtv[4];
    #pragma unroll
    for (int r = 0; r < 4; ++r){
      const int bm = lq * 4 + r;
      const bool mk = t < (int)((lpack >> (8 * r)) & 255u);
      float hnv[2];
      #pragma unroll
      for (int nt = 0; nt < 2; ++nt){
        float gi = fclamp20(acc[0][nt][r]), gf = fclamp20(acc[1][nt][r]);
        float gg = fclamp20(acc[2][nt][r]), go = fclamp20(acc[3][nt][r]);
        float ei = __builtin_amdgcn_exp2f(-1.4426950408889634f * gi);
        float ef = __builtin_amdgcn_exp2f(-1.4426950408889634f * gf);
        float eg = __builtin_amdgcn_exp2f(-2.8853900817779268f * gg);
        float d1 = (1.0f + ei) * (1.0f + eg);
        float df = 1.0f + ef;
        float rD = __builtin_amdgcn_rcpf(d1 * df);
        float it = (1.0f - eg) * df * rD;          // sig(i)*tanh(g)
        float sf = d1 * rD;                        // sig(f)
        float cn = fmaf(sf, cst[nt][r], it);
        if (mk) cst[nt][r] = cn;
        float eo = __builtin_amdgcn_exp2f(-1.4426950408889634f * go);
        float ec = __builtin_amdgcn_exp2f(-2.8853900817779268f * fclamp20(cn));
        float r2 = __builtin_amdgcn_rcpf((1.0f + eo) * (1.0f + ec));
        hnv[nt] = (1.0f - ec) * r2;                // sig(o)*tanh(cn)
      }
      int pk = __builtin_amdgcn_cvt_pk_fp8_f32(hnv[0], hnv[1], 0, false);
      us16 p16 = (us16)(pk & 0xFFFF);
      if (mk) hst[r] = p16;
      houtv[r] = mk ? p16 : (us16)0;
      *(us16*)&nxt[bm * SA + w * 32 + lrow * 2] = hst[r];
    }

    if constexpr (!GIN){
      if (tau < 199){
        int tn = rev ? (198 - tau) : (tau + 1);
        if (tid < (16 * XDIM) >> 3){
          int r = tid / (XDIM >> 3), c8 = (tid % (XDIM >> 3)) * 8;
          *(long*)&nxt[r * SA + 256 + c8] =
            *(const long*)&xbuf[((long)(b0 + r) * 200 + tn) * XDIM + c8];
        }
      }
    }
    __syncthreads();
    #pragma unroll
    for (int r = 0; r < 4; ++r){
      *(us16*)hp[r] = houtv[r];
      hp[r] += dstep;
    }
  }
}

__global__ __launch_bounds__(512, 2) void k_lstm(
    const u8* __restrict__ char_vec, const u8* __restrict__ gin,
    const u8* __restrict__ wsw_cf, const u8* __restrict__ wsw_cb,
    const u8* __restrict__ wsw_wf, const u8* __restrict__ wsw_wb,
    const float* __restrict__ b_cf, const float* __restrict__ b_cb,
    const int* __restrict__ len_char, const int* __restrict__ len_word,
    u8* __restrict__ h_char, u8* __restrict__ h_word)
{
  const int dir   = blockIdx.x >> 4;
  const int slice = blockIdx.x & 15;
  const int b0 = slice * 16;
  __shared__ __align__(16) u8 abuf[2 * 16 * 304];

  if (dir == 0)
    lstm_body<9, 32, 304, false>(abuf, char_vec, nullptr, wsw_cf, b_cf,
                                 len_char, h_char, b0, 0, false, 0);
  else if (dir == 1)
    lstm_body<9, 32, 304, false>(abuf, char_vec, nullptr, wsw_cb, b_cb,
                                 len_char, h_char, b0, 256, true, 0);
  else if (dir == 2)
    lstm_body<8, 0, 280, true>(abuf, nullptr, gin, wsw_wf, nullptr,
                               len_word, h_word, b0, 0, false, (long)slice * 200);
  else
    lstm_body<8, 0, 280, true>(abuf, nullptr, gin, wsw_wb, nullptr,
                               len_word, h_word, b0, 256, true, (long)(16 + slice) * 200);
}

// ---------- fp8 FF GEMM body: out = softplus(A[M,KC2*64]fp8 @ Wsw^T + bias) ----------
// 64-wide k staging (2 barriers per 64 k), M=128 x N=NT*16 tile per block.
template<int NT>
DEV void gemm8_body(const u8* __restrict__ A, int KC2, const u8* __restrict__ Wsw,
                    const float* __restrict__ bias, int N,
                    void* __restrict__ outp, int ostride, int ocol0, int out_f32,
                    int m0base, int ntbase, u8* lds)
{
  const int tid = threadIdx.x;
  const int w = tid >> 6, L = tid & 63;
  const int lrow = L & 15, lq = L >> 4;
  const int Kd = KC2 * 64;
  const int KCs = KC2 * 2;
  const long* WswV = (const long*)Wsw;
  f32x4 acc[NT][2];
  #pragma unroll
  for (int nt = 0; nt < NT; ++nt){ acc[nt][0] = (f32x4){0,0,0,0}; acc[nt][1] = (f32x4){0,0,0,0}; }
  const int srow = tid >> 1, scol = (tid & 1) * 32;

  for (int kc2 = 0; kc2 < KC2; ++kc2){
    const long ab = (long)(m0base + srow) * Kd + kc2 * 64 + scol;
    i32x4 v0 = *(const i32x4*)&A[ab];
    i32x4 v1 = *(const i32x4*)&A[ab + 16];
    *(long*)&lds[srow * 72 + scol]      = ((const long*)&v0)[0];
    *(long*)&lds[srow * 72 + scol + 8]  = ((const long*)&v0)[1];
    *(long*)&lds[srow * 72 + scol + 16] = ((const long*)&v1)[0];
    *(long*)&lds[srow * 72 + scol + 24] = ((const long*)&v1)[1];
    __syncthreads();
    long af[2][2];
    #pragma unroll
    for (int m0 = 0; m0 < 2; ++m0)
      #pragma unroll
      for (int kk = 0; kk < 2; ++kk)
        af[m0][kk] = *(const long*)&lds[(w * 32 + m0 * 16 + lrow) * 72 + kk * 32 + lq * 8];
    #pragma unroll
    for (int kk = 0; kk < 2; ++kk)
      #pragma unroll
      for (int nt = 0; nt < NT; ++nt){
        long bf = WswV[((ntbase + nt) * KCs + kc2 * 2 + kk) * 64 + L];
        acc[nt][0] = mfma16f8(af[0][kk], bf, acc[nt][0]);
        acc[nt][1] = mfma16f8(af[1][kk], bf, acc[nt][1]);
      }
    __syncthreads();
  }
  #pragma unroll
  for (int nt = 0; nt < NT; ++nt){
    const int col = (ntbase + nt) * 16 + lrow;
    if (col >= N) continue;
    const float bvv = bias[col];
    #pragma unroll
    for (int m0 = 0; m0 < 2; ++m0){
      #pragma unroll
      for (int r = 0; r < 4; ++r){
        float v = fsoftplus(acc[nt][m0][r] + bvv);
        const long row = m0base + w * 32 + m0 * 16 + lq * 4 + r;
        if (out_f32) ((float*)outp)[row * ostride + ocol0 + col] = v;
        else         ((u8*)outp)[row * ostride + ocol0 + col] = f2fp8(v);
      }
    }
  }
}

// G1+G2 merged: y<4 -> h_char GEMM (cols 0..511); y=4,5 -> h_word GEMM (cols 512..711)
__global__ __launch_bounds__(256) void k_g12(
    const u8* __restrict__ hc, const u8* __restrict__ hw,
    const u8* __restrict__ w1, const u8* __restrict__ w2,
    const float* __restrict__ b1, const float* __restrict__ b2,
    u8* __restrict__ xcat)
{
  __shared__ __align__(16) u8 lds[128 * 72];
  const int y = blockIdx.y;
  if (y < 4)
    gemm8_body<8>(hc, 8, w1, b1, 512, xcat, 768, 0, 0, blockIdx.x * 128, y * 8, lds);
  else
    gemm8_body<8>(hw, 8, w2, b2, 200, xcat, 768, 512, 0, blockIdx.x * 128, (y - 4) * 8, lds);
}

template<int NT>
__global__ __launch_bounds__(256) void k_gemm8(
    const u8* __restrict__ A, int KC2, const u8* __restrict__ Wsw,
    const float* __restrict__ bias, int N,
    void* __restrict__ outp, int ostride, int out_f32)
{
  __shared__ __align__(16) u8 lds[128 * 72];
  gemm8_body<NT>(A, KC2, Wsw, bias, N, outp, ostride, 0, out_f32,
                 blockIdx.x * 128, blockIdx.y * NT, lds);
}

// ---------- CRF NLL: one wave per batch row, logits staged in LDS ----------
__global__ void k_crf(const float* __restrict__ logits, const int* __restrict__ tags,
                      const int* __restrict__ lens, const float* __restrict__ trans,
                      float* __restrict__ nll)
{
  const int b = blockIdx.x;
  const int lane = threadIdx.x;            // 64
  __shared__ float sl[2400];               // [t][12]
  __shared__ float alpha[12];
  __shared__ float tmp[12];
  for (int e = lane; e < 2400; e += 64) sl[e] = logits[(long)b * 2400 + e];
  float tcol[12];
  if (lane < 12){
    #pragma unroll
    for (int i = 0; i < 12; ++i) tcol[i] = trans[i * 12 + lane];
    alpha[lane] = 0.0f;
  }
  const int len = lens[b];
  __syncthreads();
  for (int t = 0; t < len; ++t){
    float an = 0.0f;
    if (lane < 12){
      float mx = -3.0e38f;
      #pragma unroll
      for (int i = 0; i < 12; ++i) mx = fmaxf(mx, alpha[i] + tcol[i]);
      float ss = 0.0f;
      #pragma unroll
      for (int i = 0; i < 12; ++i)
        ss += __builtin_amdgcn_exp2f(1.4426950408889634f * (alpha[i] + tcol[i] - mx));
      an = sl[t * 12 + lane] + mx + 0.69314718055994531f * __builtin_amdgcn_logf(ss);
    }
    __syncthreads();
    if (lane < 12) alpha[lane] = an;
    __syncthreads();
  }
  if (lane < 12) tmp[lane] = alpha[lane] + trans[lane * 12 + 11];
  __syncthreads();
  float rs = 0.0f;
  for (int t = lane; t < len; t += 64){
    int tg = tags[b * 200 + t];
    int pv = (t == 0) ? 10 : tags[b * 200 + t - 1];                 // START=10
    rs += sl[t * 12 + tg] + trans[pv * 12 + tg];
  }
  #pragma unroll
  for (int off = 32; off > 0; off >>= 1) rs += __shfl_down(rs, off, 64);
  if (lane == 0){
    float mx = -3.0e38f;
    for (int i = 0; i < 12; ++i) mx = fmaxf(mx, tmp[i]);
    float ss = 0.0f;
    for (int i = 0; i < 12; ++i)
      ss += __builtin_amdgcn_exp2f(1.4426950408889634f * (tmp[i] - mx));
    float total = mx + 0.69314718055994531f * __builtin_amdgcn_logf(ss);
    rs += trans[tags[b * 200 + len - 1] * 12 + 11];
    nll[b] = total - rs;
  }
}

__global__ void k_sum(const float* __restrict__ nll, float* __restrict__ out){
  __shared__ float red[256];
  int t = threadIdx.x;
  red[t] = nll[t];
  __syncthreads();
  for (int s = 128; s > 0; s >>= 1){
    if (t < s) red[t] += red[t + s];
    __syncthreads();
  }
  if (t == 0) out[0] = red[0];
}

// ---------- launcher ----------
extern "C" void kernel_launch(void* const* d_in, const int* in_sizes, int n_in,
                              void* d_out, int out_size, void* d_ws, size_t ws_size,
                              hipStream_t stream)
{
  (void)in_sizes; (void)n_in; (void)out_size; (void)ws_size;
  const int*   characters = (const int*)  d_in[0];
  const float* words      = (const float*)d_in[1];
  const int*   tags       = (const int*)  d_in[2];
  const int*   len_char   = (const int*)  d_in[3];
  const int*   len_word   = (const int*)  d_in[4];
  const float* char_emb   = (const float*)d_in[5];
  const float* char_Wih_f = (const float*)d_in[6];
  const float* char_Whh_f = (const float*)d_in[7];
  const float* char_b_f   = (const float*)d_in[8];
  const float* char_Wih_b = (const float*)d_in[9];
  const float* char_Whh_b = (const float*)d_in[10];
  const float* char_b_b   = (const float*)d_in[11];
  const float* char_lin_W = (const float*)d_in[12];
  const float* char_lin_b = (const float*)d_in[13];
  const float* word_Wih_f = (const float*)d_in[14];
  const float* word_Whh_f = (const float*)d_in[15];
  const float* word_b_f   = (const float*)d_in[16];
  const float* word_Wih_b = (const float*)d_in[17];
  const float* word_Whh_b = (const float*)d_in[18];
  const float* word_b_b   = (const float*)d_in[19];
  const float* word_lin_W = (const float*)d_in[20];
  const float* word_lin_b = (const float*)d_in[21];
  const float* lin1_W     = (const float*)d_in[22];
  const float* lin1_b     = (const float*)d_in[23];
  const float* lin2_W     = (const float*)d_in[24];
  const float* lin2_b     = (const float*)d_in[25];
  const float* tag_W      = (const float*)d_in[26];
  const float* tag_b      = (const float*)d_in[27];
  const float* trans      = (const float*)d_in[28];

  char* ws = (char*)d_ws;
  size_t off = 0;
  auto take = [&](size_t bytes) -> char* {
    char* p = ws + off;
    off = (off + bytes + 511) & ~(size_t)511;
    return p;
  };
  u8*   char_vec = (u8*)take((size_t)256*200*32);
  u8*   words_f8 = (u8*)take((size_t)256*200*128);
  u8*   wsw_cf   = (u8*)take((size_t)64*9*512);
  u8*   wsw_cb   = (u8*)take((size_t)64*9*512);
  u8*   wsw_wf   = (u8*)take((size_t)64*8*512);
  u8*   wsw_wb   = (u8*)take((size_t)64*8*512);
  u8*   wswgin_f = (u8*)take((size_t)64*4*512);
  u8*   wswgin_b = (u8*)take((size_t)64*4*512);
  u8*   wswg1    = (u8*)take((size_t)32*16*512);   // N=512 Kd=512 perm
  u8*   wswg2    = (u8*)take((size_t)16*16*512);   // N=200 Kd=512 perm
  u8*   wswg3    = (u8*)take((size_t)32*24*512);   // N=512 Kd=712(->768)
  u8*   wswg4    = (u8*)take((size_t)16*16*512);   // N=256 Kd=512
  u8*   wswg5    = (u8*)take((size_t)1*8*512);     // N=12  Kd=256
  float* logits  = (float*)take((size_t)51200*12*4);
  float* nll     = (float*)take((size_t)256*4);
  u8*   h_char   = (u8*)take((size_t)51200*512);   // 25 MB fp8 (pi-permuted)
  u8*   h_word   = (u8*)take((size_t)51200*512);   // 25 MB fp8
  u8*   gin      = (u8*)take((size_t)105*1024*1024);  // region, reused post-lstm
  u8*   x_cat    = gin;                            // 51200*768 = 38.4 MB
  u8*   x1       = gin + (size_t)40*1024*1024;     // 51200*512 = 25.6 MB
  u8*   x2       = gin + (size_t)68*1024*1024;     // 51200*256 = 12.8 MB

  // preprocessing
  k_embed<<<6400, 256, 0, stream>>>(characters, char_emb, char_vec);
  k_cvt8<<<(256*200*128 + 255)/256, 256, 0, stream>>>(words, words_f8, 256*200*128);
  k_swz_lstm<<<(64*9*512 + 255)/256, 256, 0, stream>>>(char_Whh_f, char_Wih_f, 30, 9, wsw_cf);
  k_swz_lstm<<<(64*9*512 + 255)/256, 256, 0, stream>>>(char_Whh_b, char_Wih_b, 30, 9, wsw_cb);
  k_swz_lstm<<<(64*8*512 + 255)/256, 256, 0, stream>>>(word_Whh_f, word_Wih_f, 0, 8, wsw_wf);
  k_swz_lstm<<<(64*8*512 + 255)/256, 256, 0, stream>>>(word_Whh_b, word_Wih_b, 0, 8, wsw_wb);
  k_swz_gin<<<(64*4*512 + 255)/256, 256, 0, stream>>>(word_Wih_f, wswgin_f);
  k_swz_gin<<<(64*4*512 + 255)/256, 256, 0, stream>>>(word_Wih_b, wswgin_b);
  k_swz_ff8<<<(32*16*512 + 255)/256, 256, 0, stream>>>(char_lin_W, 512, 512, 16, 1, wswg1, 32*16*512);
  k_swz_ff8<<<(16*16*512 + 255)/256, 256, 0, stream>>>(word_lin_W, 200, 512, 16, 1, wswg2, 16*16*512);
  k_swz_ff8<<<(32*24*512 + 255)/256, 256, 0, stream>>>(lin1_W, 512, 712, 24, 0, wswg3, 32*24*512);
  k_swz_ff8<<<(16*16*512 + 255)/256, 256, 0, stream>>>(lin2_W, 256, 512, 16, 0, wswg4, 16*16*512);
  k_swz_ff8<<<(1*8*512 + 255)/256, 256, 0, stream>>>(tag_W, 12, 256, 8, 0, wswg5, 1*8*512);

  // gin precompute
  k_gin<<<1600, 512, 0, stream>>>(words_f8, wswgin_f, wswgin_b, word_b_f, word_b_b, gin);

  // recurrences
  k_lstm<<<64, 512, 0, stream>>>(char_vec, gin, wsw_cf, wsw_cb, wsw_wf, wsw_wb,
                                 char_b_f, char_b_b, len_char, len_word, h_char, h_word);

  // x_cat pad (aliases gin -> after k_lstm)
  k_zpad8<<<(51200*56 + 255)/256, 256, 0, stream>>>(x_cat);

  // feed-forward chain (all fp8)
  k_g12<<<dim3(400, 6), 256, 0, stream>>>(h_char, h_word, wswg1, wswg2,
                                          char_lin_b, word_lin_b, x_cat);
  k_gemm8<8><<<dim3(400, 4), 256, 0, stream>>>(x_cat, 12, wswg3, lin1_b, 512, x1, 512, 0);
  k_gemm8<8><<<dim3(400, 2), 256, 0, stream>>>(x1,     8, wswg4, lin2_b, 256, x2, 256, 0);
  k_gemm8<1><<<dim3(400, 1), 256, 0, stream>>>(x2,     4, wswg5, tag_b,   12, logits, 12, 1);

  // CRF
  k_crf<<<256, 64, 0, stream>>>(logits, tags, len_char, trans, nll);
  k_sum<<<1, 256, 0, stream>>>(nll, (float*)d_out);
}

// Round 9
// 836.305 us; speedup vs baseline: 1.2005x; 1.2005x over previous
//
#include <hip/hip_runtime.h>
#include <cstdint>

// ---------- types / helpers ----------
typedef __attribute__((ext_vector_type(8))) short short8;
typedef __attribute__((ext_vector_type(4))) float f32x4;
typedef __attribute__((ext_vector_type(2))) float f32x2;
typedef __attribute__((ext_vector_type(4))) int i32x4;
typedef unsigned short us16;
typedef unsigned char u8;

#define DEV __device__ __forceinline__

DEV us16 f2bf(float f){
  union { float f; unsigned u; } v; v.f = f;
  unsigned r = (v.u + 0x7FFFu + ((v.u >> 16) & 1u)) >> 16;   // RNE
  return (us16)r;
}
DEV u8 f2fp8(float f){      // OCP e4m3fn via HW cvt (RNE, saturating)
  int p = __builtin_amdgcn_cvt_pk_fp8_f32(f, f, 0, false);
  return (u8)(p & 0xFF);
}
template<int SEL> DEV float fp8tof(int dw){
#if __has_builtin(__builtin_amdgcn_cvt_f32_fp8)
  return __builtin_amdgcn_cvt_f32_fp8(dw, SEL);
#else
  int b = (dw >> (8*SEL)) & 255;
  int e = (b>>3)&15, m = b&7;
  float v;
  if (e){ union{unsigned u; float f;} x; x.u = (unsigned)(((e+120)<<23) | (m<<20)); v = x.f; }
  else v = (float)m * 0.001953125f;
  return (b & 128) ? -v : v;
#endif
}
DEV f32x4 dq8x4(int dw){
#if __has_builtin(__builtin_amdgcn_cvt_pk_f32_fp8)
  f32x2 lo = __builtin_amdgcn_cvt_pk_f32_fp8(dw, false);
  f32x2 hi = __builtin_amdgcn_cvt_pk_f32_fp8(dw, true);
  return (f32x4){lo.x, lo.y, hi.x, hi.y};
#else
  return (f32x4){fp8tof<0>(dw), fp8tof<1>(dw), fp8tof<2>(dw), fp8tof<3>(dw)};
#endif
}
DEV float fsig(float x){
  float e = __builtin_amdgcn_exp2f(-1.4426950408889634f * x);
  return __builtin_amdgcn_rcpf(1.0f + e);
}
DEV float ftanh(float x){
  float e = __builtin_amdgcn_exp2f(-2.8853900817779268f * x);
  return fmaf(2.0f, __builtin_amdgcn_rcpf(1.0f + e), -1.0f);
}
DEV float fsoftplus(float x){
  float ax = fabsf(x);
  float e = __builtin_amdgcn_exp2f(-1.4426950408889634f * ax);
  float l = 0.69314718055994531f * __builtin_amdgcn_logf(1.0f + e);
  return fmaxf(x, 0.0f) + l;
}
DEV f32x4 mfma16f8(long a, long b, f32x4 c){
  return __builtin_amdgcn_mfma_f32_16x16x32_fp8_fp8(a, b, c, 0, 0, 0);
}
DEV unsigned pk4fp8(float a, float b, float c, float d){
  unsigned lo = (unsigned)__builtin_amdgcn_cvt_pk_fp8_f32(a, b, 0, false) & 0xFFFFu;
  unsigned hi = (unsigned)__builtin_amdgcn_cvt_pk_fp8_f32(c, d, 0, false) & 0xFFFFu;
  return lo | (hi << 16);
}

// Dims: B=256, T=WN=200, HH=256/dir, gates=1024, tags K=12.
// MFMA 16x16x32 fragments: A: lane L holds A[m=L&15][k=(L>>4)*8+j];
// B: lane L holds B[k=(L>>4)*8+j][n=L&15]; D: lane L reg r = D[(L>>4)*4+r][L&15].
// pi h-permutation: orig col w*32+nt*16+l -> stored w*32+l*2+nt;
// inverse: s -> (s>>5)*32 + (s&1)*16 + ((s&31)>>1)

// ---------- preprocessing ----------

__global__ void k_embed(const int* __restrict__ chars, const float* __restrict__ emb,
                        u8* __restrict__ out){
  int tid = blockIdx.x * 256 + threadIdx.x;          // 256*200*32
  if (tid >= 256*200*32) return;
  int c = tid & 31, bt = tid >> 5;
  int idx = chars[bt];
  float v = (c < 30) ? emb[idx * 30 + c] : 0.0f;
  out[tid] = f2fp8(v);
}

__global__ void k_cvt8(const float* __restrict__ src, u8* __restrict__ dst, int n){
  int tid = blockIdx.x * 256 + threadIdx.x;
  if (tid < n) dst[tid] = f2fp8(src[tid]);
}

// LSTM weight swizzle core: [w(8)][gt(4)][nt(2)][kc(KC)][lane x 8B], pi-perm h ks
DEV void swz_lstm_one(int tid, const float* Whh, const float* Wih, int I, int KC, u8* dst){
  int e = tid & 511, chunk = tid >> 9;
  int L = e >> 3, j = e & 7;
  int kc = chunk % KC; int rem = chunk / KC;
  int nt = rem & 1, gt = (rem >> 1) & 3, w = rem >> 3;
  int g = gt * 256 + w * 32 + nt * 16 + (L & 15);
  int s = kc * 32 + (L >> 4) * 8 + j;
  float v = 0.0f;
  if (s < 256){
    int k = (s >> 5) * 32 + (s & 1) * 16 + ((s & 31) >> 1);
    v = Whh[g * 256 + k];
  } else {
    int xi = s - 256;
    if (xi < I) v = Wih[g * I + xi];
  }
  dst[tid] = f2fp8(v);
}

// all 4 LSTM dirs in one launch: blocks [0,1152) cf, [1152,2304) cb,
// [2304,3328) wf, [3328,4352) wb
__global__ void k_swz_lstm4(
    const float* __restrict__ WhhA, const float* __restrict__ WihA, u8* dA,
    const float* __restrict__ WhhB, const float* __restrict__ WihB, u8* dB,
    const float* __restrict__ WhhC, u8* dC,
    const float* __restrict__ WhhD, u8* dD)
{
  int b = blockIdx.x;
  if (b < 1152)       swz_lstm_one(b * 256 + threadIdx.x, WhhA, WihA, 30, 9, dA);
  else if (b < 2304)  swz_lstm_one((b - 1152) * 256 + threadIdx.x, WhhB, WihB, 30, 9, dB);
  else if (b < 3328)  swz_lstm_one((b - 2304) * 256 + threadIdx.x, WhhC, nullptr, 0, 8, dC);
  else                swz_lstm_one((b - 3328) * 256 + threadIdx.x, WhhD, nullptr, 0, 8, dD);
}

// Wih (word) B-frag swizzle, both dirs: [ntile(64)][kc(4)][lane x 8B]
__global__ void k_swz_gin2(const float* __restrict__ Wf, const float* __restrict__ Wb,
                           u8* __restrict__ df, u8* __restrict__ db){
  int b = blockIdx.x;
  const float* W = (b < 512) ? Wf : Wb;
  u8* dst = (b < 512) ? df : db;
  int tid = ((b < 512) ? b : b - 512) * 256 + threadIdx.x;
  int e = tid & 511, chunk = tid >> 9;
  int L = e >> 3, j = e & 7;
  int kc = chunk & 3, ntile = chunk >> 2;
  int g = ntile * 16 + (L & 15);
  int k = kc * 32 + (L >> 4) * 8 + j;
  dst[tid] = f2fp8(W[g * 128 + k]);
}

// B-frag fp8 swizzle core: [nt][kc(KCs)][lane x 8]; perm => pi within 256-halves
DEV void swz_ffB_one(int tid, const float* W, int N, int Kd, int KCs, int perm, u8* dst){
  int e = tid & 511, chunk = tid >> 9;
  int L = e >> 3, j = e & 7;
  int kc = chunk % KCs; int nt = chunk / KCs;
  int g = nt * 16 + (L & 15);
  int s = kc * 32 + (L >> 4) * 8 + j;
  int k;
  if (perm){ int base = s & ~255; int q = s & 255;
             k = base + (q >> 5) * 32 + (q & 1) * 16 + ((q & 31) >> 1); }
  else k = s;
  float v = (g < N && k < Kd) ? W[g * Kd + k] : 0.0f;
  dst[tid] = f2fp8(v);
}

// g1 [0,1024) g2 [1024,1536) g5 [1536,1552)
__global__ void k_swz_ffB(const float* __restrict__ W1, u8* d1,
                          const float* __restrict__ W2, u8* d2,
                          const float* __restrict__ W5, u8* d5){
  int b = blockIdx.x;
  if (b < 1024)      swz_ffB_one(b * 256 + threadIdx.x, W1, 512, 512, 16, 1, d1);
  else if (b < 1536) swz_ffB_one((b - 1024) * 256 + threadIdx.x, W2, 200, 512, 16, 1, d2);
  else               swz_ffB_one((b - 1536) * 256 + threadIdx.x, W5, 12, 256, 8, 0, d5);
}

// A-frag fp8 swizzle core: [mt][kc(KCs)][lane x 8]; A[m=mt*16+(L&15)][k]
DEV void swz_ffA_one(int tid, const float* W, int Kd, int KCs, u8* dst){
  int e = tid & 511, chunk = tid >> 9;
  int L = e >> 3, j = e & 7;
  int kc = chunk % KCs; int mt = chunk / KCs;
  int m = mt * 16 + (L & 15);
  int k = kc * 32 + (L >> 4) * 8 + j;
  float v = (k < Kd) ? W[m * Kd + k] : 0.0f;
  dst[tid] = f2fp8(v);
}

// g3 (lin1: 512x712, KCs=24) [0,1536); g4 (lin2: 256x512, KCs=16) [1536,2048)
__global__ void k_swz_ffA(const float* __restrict__ W3, u8* d3,
                          const float* __restrict__ W4, u8* d4){
  int b = blockIdx.x;
  if (b < 1536) swz_ffA_one(b * 256 + threadIdx.x, W3, 712, 24, d3);
  else          swz_ffA_one((b - 1536) * 256 + threadIdx.x, W4, 512, 16, d4);
}

// ---------- gin precompute: gin = fp8(x @ Wih^T + b), 4 timesteps/block ----------
__global__ __launch_bounds__(512) void k_gin(
    const u8* __restrict__ words_f8, const u8* __restrict__ wswg_f,
    const u8* __restrict__ wswg_b, const float* __restrict__ bias_f,
    const float* __restrict__ bias_b, u8* __restrict__ gin)
{
  const int blk = blockIdx.x;
  const int d = blk / 800, rem = blk - d * 800;
  const int slice = rem / 50, tq = rem - slice * 50;
  const u8* Wsw = d ? wswg_b : wswg_f;
  const float* bias = d ? bias_b : bias_f;
  __shared__ u8 xs[16 * 136];
  __shared__ u8 sbuf[512 * 32];
  const int tid = threadIdx.x;
  const int wv = tid >> 6, L = tid & 63;
  const int lrow = L & 15, lq = L >> 4;
  const long* WswV = (const long*)Wsw;

  long wr[8][4];
  #pragma unroll
  for (int nt = 0; nt < 8; ++nt)
    #pragma unroll
    for (int kc = 0; kc < 4; ++kc)
      wr[nt][kc] = WswV[((wv * 8 + nt) * 4 + kc) * 64 + L];
  float bv[8];
  #pragma unroll
  for (int nt = 0; nt < 8; ++nt) bv[nt] = bias[wv * 128 + nt * 16 + lrow];

  for (int i = 0; i < 4; ++i){
    const int t = tq * 4 + i;
    if (tid < 256){
      int r = tid >> 4, c8 = (tid & 15) * 8;
      *(long*)&xs[r * 136 + c8] =
        *(const long*)&words_f8[((long)(slice * 16 + r) * 200 + t) * 128 + c8];
    }
    __syncthreads();
    f32x4 acc[8];
    #pragma unroll
    for (int nt = 0; nt < 8; ++nt) acc[nt] = (f32x4){bv[nt], bv[nt], bv[nt], bv[nt]};
    #pragma unroll
    for (int kc = 0; kc < 4; ++kc){
      long af = *(const long*)&xs[lrow * 136 + kc * 32 + lq * 8];
      #pragma unroll
      for (int nt = 0; nt < 8; ++nt)
        acc[nt] = mfma16f8(af, wr[nt][kc], acc[nt]);
    }
    #pragma unroll
    for (int nt = 0; nt < 8; ++nt){
      int gcol = wv * 128 + nt * 16 + lrow;
      int gt = gcol >> 8, w2 = (gcol >> 5) & 7, nt2 = (gcol >> 4) & 1;
      int tid2 = w2 * 64 + lq * 16 + lrow;
      #pragma unroll
      for (int r = 0; r < 4; ++r)
        sbuf[tid2 * 32 + gt * 8 + nt2 * 4 + r] = f2fp8(acc[nt][r]);
    }
    __syncthreads();
    long ob = (((long)(d * 16 + slice) * 200 + t) * 512 + tid) * 32;
    *(i32x4*)&gin[ob]      = *(const i32x4*)&sbuf[tid * 32];
    *(i32x4*)&gin[ob + 16] = *(const i32x4*)&sbuf[tid * 32 + 16];
    __syncthreads();
  }
}

// ---------- bidirectional LSTM (R7 structure, measured 441 us) ----------
template<int KC, int XDIM, int SA, bool GIN>
DEV void lstm_body(u8* abuf, const u8* __restrict__ xbuf, const u8* __restrict__ gin,
                   const u8* __restrict__ Wsw, const float* __restrict__ bias,
                   const int* __restrict__ lens, u8* __restrict__ hout,
                   int b0, int hcol0, bool rev, long ginBase)
{
  constexpr int BUF = 16 * SA;
  const int tid = threadIdx.x;
  const int w = tid >> 6, L = tid & 63;
  const int lrow = L & 15, lq = L >> 4;
  const long* WswV = (const long*)Wsw;

  long wr[4][2][KC];
  #pragma unroll
  for (int gt = 0; gt < 4; ++gt)
    #pragma unroll
    for (int nt = 0; nt < 2; ++nt)
      #pragma unroll
      for (int kc = 0; kc < KC; ++kc)
        wr[gt][nt][kc] = WswV[(((w * 4 + gt) * 2 + nt) * KC + kc) * 64 + L];

  float bv[4][2];
  if constexpr (!GIN){
    #pragma unroll
    for (int gt = 0; gt < 4; ++gt)
      #pragma unroll
      for (int nt = 0; nt < 2; ++nt)
        bv[gt][nt] = bias[gt * 256 + w * 32 + nt * 16 + lrow];
  }

  unsigned lpack = 0;
  #pragma unroll
  for (int r = 0; r < 4; ++r)
    lpack |= (unsigned)lens[b0 + lq * 4 + r] << (8 * r);

  float cst[2][4];
  us16 hst[4];
  #pragma unroll
  for (int r = 0; r < 4; ++r){ hst[r] = 0; cst[0][r] = 0.0f; cst[1][r] = 0.0f; }

  for (int e = tid; e < 16 * 32; e += 512)
    *(long*)&abuf[(e >> 5) * SA + (e & 31) * 8] = 0;

  const int t0 = rev ? 199 : 0;
  if constexpr (!GIN){
    if (tid < (16 * XDIM) >> 3){
      int r = tid / (XDIM >> 3), c8 = (tid % (XDIM >> 3)) * 8;
      *(long*)&abuf[r * SA + 256 + c8] =
        *(const long*)&xbuf[((long)(b0 + r) * 200 + t0) * XDIM + c8];
    }
  }
  i32x4 gA{}, gB{};
  if constexpr (GIN){
    const u8* gp = gin + ((ginBase + t0) * 512 + tid) * 32;
    gA = *(const i32x4*)gp; gB = *(const i32x4*)(gp + 16);
  }
  __syncthreads();

  for (int tau = 0; tau < 200; ++tau){
    const int t = rev ? (199 - tau) : tau;
    u8* cur = abuf + (tau & 1) * BUF;
    u8* nxt = abuf + ((tau & 1) ^ 1) * BUF;

    f32x4 acc[4][2];
    if constexpr (GIN){
      int g4[8];
      *(i32x4*)&g4[0] = gA; *(i32x4*)&g4[4] = gB;
      #pragma unroll
      for (int gt = 0; gt < 4; ++gt)
        #pragma unroll
        for (int nt = 0; nt < 2; ++nt)
          acc[gt][nt] = dq8x4(g4[gt * 2 + nt]);
      int tn = (tau < 199) ? (rev ? 198 - tau : tau + 1) : t;
      const u8* gp = gin + ((ginBase + tn) * 512 + tid) * 32;
      gA = *(const i32x4*)gp; gB = *(const i32x4*)(gp + 16);
    } else {
      #pragma unroll
      for (int gt = 0; gt < 4; ++gt)
        #pragma unroll
        for (int nt = 0; nt < 2; ++nt)
          acc[gt][nt] = (f32x4){bv[gt][nt], bv[gt][nt], bv[gt][nt], bv[gt][nt]};
    }

    #pragma unroll
    for (int kc = 0; kc < KC; ++kc){
      long af = *(const long*)&cur[lrow * SA + kc * 32 + lq * 8];
      #pragma unroll
      for (int gt = 0; gt < 4; ++gt)
        #pragma unroll
        for (int nt = 0; nt < 2; ++nt)
          acc[gt][nt] = mfma16f8(af, wr[gt][nt][kc], acc[gt][nt]);
    }

    // epilogue (R7 form): fsig/ftanh, packed fp8 pair per r
    us16 houtv[4];
    #pragma unroll
    for (int r = 0; r < 4; ++r){
      const int bm = lq * 4 + r;
      const bool mk = t < (int)((lpack >> (8 * r)) & 255u);
      float hnv[2];
      #pragma unroll
      for (int nt = 0; nt < 2; ++nt){
        float gi = acc[0][nt][r], gf = acc[1][nt][r];
        float gg = acc[2][nt][r], go = acc[3][nt][r];
        float cn = fsig(gf) * cst[nt][r] + fsig(gi) * ftanh(gg);
        if (mk) cst[nt][r] = cn;
        hnv[nt] = fsig(go) * ftanh(cn);
      }
      int pk = __builtin_amdgcn_cvt_pk_fp8_f32(hnv[0], hnv[1], 0, false);
      us16 p16 = (us16)(pk & 0xFFFF);
      if (mk) hst[r] = p16;
      houtv[r] = mk ? p16 : (us16)0;
      *(us16*)&nxt[bm * SA + w * 32 + lrow * 2] = hst[r];
    }

    if constexpr (!GIN){
      if (tau < 199){
        int tn = rev ? (198 - tau) : (tau + 1);
        if (tid < (16 * XDIM) >> 3){
          int r = tid / (XDIM >> 3), c8 = (tid % (XDIM >> 3)) * 8;
          *(long*)&nxt[r * SA + 256 + c8] =
            *(const long*)&xbuf[((long)(b0 + r) * 200 + tn) * XDIM + c8];
        }
      }
    }
    __syncthreads();
    #pragma unroll
    for (int r = 0; r < 4; ++r){
      const int bm = lq * 4 + r;
      long ga = ((long)(b0 + bm) * 200 + t) * 512 + hcol0 + w * 32 + lrow * 2;
      *(us16*)&hout[ga] = houtv[r];
    }
  }
}

__global__ __launch_bounds__(512, 2) void k_lstm(
    const u8* __restrict__ char_vec, const u8* __restrict__ gin,
    const u8* __restrict__ wsw_cf, const u8* __restrict__ wsw_cb,
    const u8* __restrict__ wsw_wf, const u8* __restrict__ wsw_wb,
    const float* __restrict__ b_cf, const float* __restrict__ b_cb,
    const int* __restrict__ len_char, const int* __restrict__ len_word,
    u8* __restrict__ h_char, u8* __restrict__ h_word)
{
  const int dir   = blockIdx.x >> 4;
  const int slice = blockIdx.x & 15;
  const int b0 = slice * 16;
  __shared__ __align__(16) u8 abuf[2 * 16 * 304];

  if (dir == 0)
    lstm_body<9, 32, 304, false>(abuf, char_vec, nullptr, wsw_cf, b_cf,
                                 len_char, h_char, b0, 0, false, 0);
  else if (dir == 1)
    lstm_body<9, 32, 304, false>(abuf, char_vec, nullptr, wsw_cb, b_cb,
                                 len_char, h_char, b0, 256, true, 0);
  else if (dir == 2)
    lstm_body<8, 0, 280, true>(abuf, nullptr, gin, wsw_wf, nullptr,
                               len_word, h_word, b0, 0, false, (long)slice * 200);
  else
    lstm_body<8, 0, 280, true>(abuf, nullptr, gin, wsw_wb, nullptr,
                               len_word, h_word, b0, 256, true, (long)(16 + slice) * 200);
}

// ---------- G1+G2 merged (fp8 GEMM into x_cat, zero-fill pad cols) ----------
// 64-wide k staging, M=128 x N=128 tile per block, B-frag weights.
DEV void g12_body(const u8* __restrict__ A, const u8* __restrict__ Wsw,
                  const float* __restrict__ bias, int N,
                  u8* __restrict__ outp, int ocol0, int m0base, int ntbase, u8* lds)
{
  const int tid = threadIdx.x;
  const int w = tid >> 6, L = tid & 63;
  const int lrow = L & 15, lq = L >> 4;
  const long* WswV = (const long*)Wsw;
  f32x4 acc[8][2] = {};
  const int srow = tid >> 1, scol = (tid & 1) * 32;

  for (int kc2 = 0; kc2 < 8; ++kc2){
    const long ab = (long)(m0base + srow) * 512 + kc2 * 64 + scol;
    i32x4 v0 = *(const i32x4*)&A[ab];
    i32x4 v1 = *(const i32x4*)&A[ab + 16];
    *(long*)&lds[srow * 72 + scol]      = ((const long*)&v0)[0];
    *(long*)&lds[srow * 72 + scol + 8]  = ((const long*)&v0)[1];
    *(long*)&lds[srow * 72 + scol + 16] = ((const long*)&v1)[0];
    *(long*)&lds[srow * 72 + scol + 24] = ((const long*)&v1)[1];
    __syncthreads();
    long af[2][2];
    #pragma unroll
    for (int m0 = 0; m0 < 2; ++m0)
      #pragma unroll
      for (int kk = 0; kk < 2; ++kk)
        af[m0][kk] = *(const long*)&lds[(w * 32 + m0 * 16 + lrow) * 72 + kk * 32 + lq * 8];
    #pragma unroll
    for (int kk = 0; kk < 2; ++kk)
      #pragma unroll
      for (int nt = 0; nt < 8; ++nt){
        long bf = WswV[((ntbase + nt) * 16 + kc2 * 2 + kk) * 64 + L];
        acc[nt][0] = mfma16f8(af[0][kk], bf, acc[nt][0]);
        acc[nt][1] = mfma16f8(af[1][kk], bf, acc[nt][1]);
      }
    __syncthreads();
  }
  #pragma unroll
  for (int nt = 0; nt < 8; ++nt){
    const int col = (ntbase + nt) * 16 + lrow;
    const bool valid = col < N;
    const float bvv = valid ? bias[col] : 0.0f;
    #pragma unroll
    for (int m0 = 0; m0 < 2; ++m0){
      #pragma unroll
      for (int r = 0; r < 4; ++r){
        float v = fsoftplus(acc[nt][m0][r] + bvv);
        const long row = m0base + w * 32 + m0 * 16 + lq * 4 + r;
        outp[row * 768 + ocol0 + col] = valid ? f2fp8(v) : (u8)0;
      }
    }
  }
}

__global__ __launch_bounds__(256) void k_g12(
    const u8* __restrict__ hc, const u8* __restrict__ hw,
    const u8* __restrict__ w1, const u8* __restrict__ w2,
    const float* __restrict__ b1, const float* __restrict__ b2,
    u8* __restrict__ xcat)
{
  __shared__ __align__(16) u8 lds[128 * 72];
  const int y = blockIdx.y;
  if (y < 4)
    g12_body(hc, w1, b1, 512, xcat,   0, blockIdx.x * 128, y * 8, lds);
  else
    g12_body(hw, w2, b2, 200, xcat, 512, blockIdx.x * 128, (y - 4) * 8, lds);
}

// ---------- fused tail: logits = sp(sp(sp(xcat@W3+b3)@W4+b4)@W5+b5) ----------
// 800 blocks x 256 thr; 64 batch rows per block; x1/x2 live in LDS only.
// Stages 1-2 use swapped MFMA roles (A=weights, B=activations) so D gives 4
// consecutive output channels per thread -> one packed ds_write_b32.
__global__ __launch_bounds__(256, 2) void k_tail(
    const u8* __restrict__ xcat, const u8* __restrict__ w3A,
    const u8* __restrict__ w4A, const u8* __restrict__ w5B,
    const float* __restrict__ b3, const float* __restrict__ b4,
    const float* __restrict__ b5, float* __restrict__ logits)
{
  __shared__ __align__(16) u8 sA[64 * 72];     // x_cat k-chunk stage
  __shared__ __align__(16) u8 x1s[64 * 520];   // [batch][512+8]
  __shared__ __align__(16) u8 x2s[64 * 264];   // [batch][256+8]
  const int tid = threadIdx.x;
  const int w = tid >> 6, L = tid & 63;
  const int lrow = L & 15, lq = L >> 4;
  const int m0 = blockIdx.x * 64;
  const long* W3 = (const long*)w3A;
  const long* W4 = (const long*)w4A;
  const long* W5 = (const long*)w5B;

  // ---- stage 1: x1 = sp(xcat @ lin1^T + b3) ; A=W3, B=xcat, D=x1^T ----
  f32x4 acc[8][4];
  #pragma unroll
  for (int mt = 0; mt < 8; ++mt)
    #pragma unroll
    for (int nt = 0; nt < 4; ++nt) acc[mt][nt] = (f32x4){0,0,0,0};
  const int srow = tid >> 2, sc = (tid & 3) * 16;

  for (int kc2 = 0; kc2 < 12; ++kc2){
    i32x4 v = *(const i32x4*)&xcat[(long)(m0 + srow) * 768 + kc2 * 64 + sc];
    *(long*)&sA[srow * 72 + sc]     = ((const long*)&v)[0];
    *(long*)&sA[srow * 72 + sc + 8] = ((const long*)&v)[1];
    __syncthreads();
    #pragma unroll
    for (int kk = 0; kk < 2; ++kk){
      long bf[4];
      #pragma unroll
      for (int nt = 0; nt < 4; ++nt)
        bf[nt] = *(const long*)&sA[(nt * 16 + lrow) * 72 + kk * 32 + lq * 8];
      #pragma unroll
      for (int mt = 0; mt < 8; ++mt){
        long af = W3[((w * 8 + mt) * 24 + kc2 * 2 + kk) * 64 + L];
        #pragma unroll
        for (int nt = 0; nt < 4; ++nt)
          acc[mt][nt] = mfma16f8(af, bf[nt], acc[mt][nt]);
      }
    }
    __syncthreads();
  }
  #pragma unroll
  for (int mt = 0; mt < 8; ++mt){
    const int ch0 = (w * 8 + mt) * 16 + lq * 4;
    f32x4 bb = *(const f32x4*)&b3[ch0];
    #pragma unroll
    for (int nt = 0; nt < 4; ++nt){
      const int bat = nt * 16 + lrow;
      unsigned pk = pk4fp8(fsoftplus(acc[mt][nt][0] + bb[0]),
                           fsoftplus(acc[mt][nt][1] + bb[1]),
                           fsoftplus(acc[mt][nt][2] + bb[2]),
                           fsoftplus(acc[mt][nt][3] + bb[3]));
      *(unsigned*)&x1s[bat * 520 + ch0] = pk;
    }
  }
  __syncthreads();

  // ---- stage 2: x2 = sp(x1 @ lin2^T + b4) ; A=W4, B=x1, D=x2^T ----
  f32x4 a2[4][4];
  #pragma unroll
  for (int mt = 0; mt < 4; ++mt)
    #pragma unroll
    for (int nt = 0; nt < 4; ++nt) a2[mt][nt] = (f32x4){0,0,0,0};
  for (int kc = 0; kc < 16; ++kc){
    long bf[4];
    #pragma unroll
    for (int nt = 0; nt < 4; ++nt)
      bf[nt] = *(const long*)&x1s[(nt * 16 + lrow) * 520 + kc * 32 + lq * 8];
    #pragma unroll
    for (int mt = 0; mt < 4; ++mt){
      long af = W4[((w * 4 + mt) * 16 + kc) * 64 + L];
      #pragma unroll
      for (int nt = 0; nt < 4; ++nt)
        a2[mt][nt] = mfma16f8(af, bf[nt], a2[mt][nt]);
    }
  }
  #pragma unroll
  for (int mt = 0; mt < 4; ++mt){
    const int ch0 = (w * 4 + mt) * 16 + lq * 4;
    f32x4 bb = *(const f32x4*)&b4[ch0];
    #pragma unroll
    for (int nt = 0; nt < 4; ++nt){
      const int bat = nt * 16 + lrow;
      unsigned pk = pk4fp8(fsoftplus(a2[mt][nt][0] + bb[0]),
                           fsoftplus(a2[mt][nt][1] + bb[1]),
                           fsoftplus(a2[mt][nt][2] + bb[2]),
                           fsoftplus(a2[mt][nt][3] + bb[3]));
      *(unsigned*)&x2s[bat * 264 + ch0] = pk;
    }
  }
  __syncthreads();

  // ---- stage 3: logits = sp(x2 @ tag^T + b5) ; normal roles ----
  f32x4 a3 = (f32x4){0,0,0,0};
  #pragma unroll
  for (int kc = 0; kc < 8; ++kc){
    long af = *(const long*)&x2s[(w * 16 + lrow) * 264 + kc * 32 + lq * 8];
    long bf = W5[kc * 64 + L];
    a3 = mfma16f8(af, bf, a3);
  }
  if (lrow < 12){
    float bb = b5[lrow];
    #pragma unroll
    for (int r = 0; r < 4; ++r)
      logits[(long)(m0 + w * 16 + lq * 4 + r) * 12 + lrow] = fsoftplus(a3[r] + bb);
  }
}

// ---------- CRF NLL: one wave per batch row, logits staged in LDS ----------
__global__ void k_crf(const float* __restrict__ logits, const int* __restrict__ tags,
                      const int* __restrict__ lens, const float* __restrict__ trans,
                      float* __restrict__ nll)
{
  const int b = blockIdx.x;
  const int lane = threadIdx.x;            // 64
  __shared__ float sl[2400];               // [t][12]
  __shared__ float alpha[12];
  __shared__ float tmp[12];
  for (int e = lane; e < 2400; e += 64) sl[e] = logits[(long)b * 2400 + e];
  float tcol[12];
  if (lane < 12){
    #pragma unroll
    for (int i = 0; i < 12; ++i) tcol[i] = trans[i * 12 + lane];
    alpha[lane] = 0.0f;
  }
  const int len = lens[b];
  __syncthreads();
  for (int t = 0; t < len; ++t){
    float an = 0.0f;
    if (lane < 12){
      float mx = -3.0e38f;
      #pragma unroll
      for (int i = 0; i < 12; ++i) mx = fmaxf(mx, alpha[i] + tcol[i]);
      float ss = 0.0f;
      #pragma unroll
      for (int i = 0; i < 12; ++i)
        ss += __builtin_amdgcn_exp2f(1.4426950408889634f * (alpha[i] + tcol[i] - mx));
      an = sl[t * 12 + lane] + mx + 0.69314718055994531f * __builtin_amdgcn_logf(ss);
    }
    __syncthreads();
    if (lane < 12) alpha[lane] = an;
    __syncthreads();
  }
  if (lane < 12) tmp[lane] = alpha[lane] + trans[lane * 12 + 11];
  __syncthreads();
  float rs = 0.0f;
  for (int t = lane; t < len; t += 64){
    int tg = tags[b * 200 + t];
    int pv = (t == 0) ? 10 : tags[b * 200 + t - 1];                 // START=10
    rs += sl[t * 12 + tg] + trans[pv * 12 + tg];
  }
  #pragma unroll
  for (int off = 32; off > 0; off >>= 1) rs += __shfl_down(rs, off, 64);
  if (lane == 0){
    float mx = -3.0e38f;
    for (int i = 0; i < 12; ++i) mx = fmaxf(mx, tmp[i]);
    float ss = 0.0f;
    for (int i = 0; i < 12; ++i)
      ss += __builtin_amdgcn_exp2f(1.4426950408889634f * (tmp[i] - mx));
    float total = mx + 0.69314718055994531f * __builtin_amdgcn_logf(ss);
    rs += trans[tags[b * 200 + len - 1] * 12 + 11];
    nll[b] = total - rs;
  }
}

__global__ void k_sum(const float* __restrict__ nll, float* __restrict__ out){
  __shared__ float red[256];
  int t = threadIdx.x;
  red[t] = nll[t];
  __syncthreads();
  for (int s = 128; s > 0; s >>= 1){
    if (t < s) red[t] += red[t + s];
    __syncthreads();
  }
  if (t == 0) out[0] = red[0];
}

// ---------- launcher ----------
extern "C" void kernel_launch(void* const* d_in, const int* in_sizes, int n_in,
                              void* d_out, int out_size, void* d_ws, size_t ws_size,
                              hipStream_t stream)
{
  (void)in_sizes; (void)n_in; (void)out_size; (void)ws_size;
  const int*   characters = (const int*)  d_in[0];
  const float* words      = (const float*)d_in[1];
  const int*   tags       = (const int*)  d_in[2];
  const int*   len_char   = (const int*)  d_in[3];
  const int*   len_word   = (const int*)  d_in[4];
  const float* char_emb   = (const float*)d_in[5];
  const float* char_Wih_f = (const float*)d_in[6];
  const float* char_Whh_f = (const float*)d_in[7];
  const float* char_b_f   = (const float*)d_in[8];
  const float* char_Wih_b = (const float*)d_in[9];
  const float* char_Whh_b = (const float*)d_in[10];
  const float* char_b_b   = (const float*)d_in[11];
  const float* char_lin_W = (const float*)d_in[12];
  const float* char_lin_b = (const float*)d_in[13];
  const float* word_Wih_f = (const float*)d_in[14];
  const float* word_Whh_f = (const float*)d_in[15];
  const float* word_b_f   = (const float*)d_in[16];
  const float* word_Wih_b = (const float*)d_in[17];
  const float* word_Whh_b = (const float*)d_in[18];
  const float* word_b_b   = (const float*)d_in[19];
  const float* word_lin_W = (const float*)d_in[20];
  const float* word_lin_b = (const float*)d_in[21];
  const float* lin1_W     = (const float*)d_in[22];
  const float* lin1_b     = (const float*)d_in[23];
  const float* lin2_W     = (const float*)d_in[24];
  const float* lin2_b     = (const float*)d_in[25];
  const float* tag_W      = (const float*)d_in[26];
  const float* tag_b      = (const float*)d_in[27];
  const float* trans      = (const float*)d_in[28];

  char* ws = (char*)d_ws;
  size_t off = 0;
  auto take = [&](size_t bytes) -> char* {
    char* p = ws + off;
    off = (off + bytes + 511) & ~(size_t)511;
    return p;
  };
  u8*   char_vec = (u8*)take((size_t)256*200*32);
  u8*   words_f8 = (u8*)take((size_t)256*200*128);
  u8*   wsw_cf   = (u8*)take((size_t)64*9*512);
  u8*   wsw_cb   = (u8*)take((size_t)64*9*512);
  u8*   wsw_wf   = (u8*)take((size_t)64*8*512);
  u8*   wsw_wb   = (u8*)take((size_t)64*8*512);
  u8*   wswgin_f = (u8*)take((size_t)64*4*512);
  u8*   wswgin_b = (u8*)take((size_t)64*4*512);
  u8*   wswg1    = (u8*)take((size_t)32*16*512);   // B-frag, perm
  u8*   wswg2    = (u8*)take((size_t)16*16*512);   // B-frag, perm
  u8*   wswg3    = (u8*)take((size_t)32*24*512);   // A-frag (lin1)
  u8*   wswg4    = (u8*)take((size_t)16*16*512);   // A-frag (lin2)
  u8*   wswg5    = (u8*)take((size_t)1*8*512);     // B-frag (tag)
  float* logits  = (float*)take((size_t)51200*12*4);
  float* nll     = (float*)take((size_t)256*4);
  u8*   h_char   = (u8*)take((size_t)51200*512);   // 25 MB fp8 (pi-permuted)
  u8*   h_word   = (u8*)take((size_t)51200*512);   // 25 MB fp8
  u8*   gin      = (u8*)take((size_t)105*1024*1024);  // reused post-lstm
  u8*   x_cat    = gin;                            // 51200*768 = 38.4 MB

  // preprocessing (4 swizzle launches total)
  k_embed<<<6400, 256, 0, stream>>>(characters, char_emb, char_vec);
  k_cvt8<<<(256*200*128 + 255)/256, 256, 0, stream>>>(words, words_f8, 256*200*128);
  k_swz_lstm4<<<4352, 256, 0, stream>>>(char_Whh_f, char_Wih_f, wsw_cf,
                                        char_Whh_b, char_Wih_b, wsw_cb,
                                        word_Whh_f, wsw_wf,
                                        word_Whh_b, wsw_wb);
  k_swz_gin2<<<1024, 256, 0, stream>>>(word_Wih_f, word_Wih_b, wswgin_f, wswgin_b);
  k_swz_ffB<<<1552, 256, 0, stream>>>(char_lin_W, wswg1, word_lin_W, wswg2, tag_W, wswg5);
  k_swz_ffA<<<2048, 256, 0, stream>>>(lin1_W, wswg3, lin2_W, wswg4);

  // gin precompute
  k_gin<<<1600, 512, 0, stream>>>(words_f8, wswgin_f, wswgin_b, word_b_f, word_b_b, gin);

  // recurrences
  k_lstm<<<64, 512, 0, stream>>>(char_vec, gin, wsw_cf, wsw_cb, wsw_wf, wsw_wb,
                                 char_b_f, char_b_b, len_char, len_word, h_char, h_word);

  // feed-forward: G1+G2 (pad fill included), then fused G3+G4+G5
  k_g12<<<dim3(400, 6), 256, 0, stream>>>(h_char, h_word, wswg1, wswg2,
                                          char_lin_b, word_lin_b, x_cat);
  k_tail<<<800, 256, 0, stream>>>(x_cat, wswg3, wswg4, wswg5,
                                  lin1_b, lin2_b, tag_b, logits);

  // CRF
  k_crf<<<256, 64, 0, stream>>>(logits, tags, len_char, trans, nll);
  k_sum<<<1, 256, 0, stream>>>(nll, (float*)d_out);
}